// Round 7
// baseline (6372.367 us; speedup 1.0000x reference)
//
#include <hip/hip_runtime.h>
#include <hip/hip_bf16.h>
#include <stdint.h>

// 2-layer LSTM, B=64, T=1024, D=H=512.
// Persistent pipelined kernel: 128 WGs = 2 layers x 4 row-islands x 16 WGs.
// Cross-WG h exchange = TAGGED u32 words ((bf16<<16)|step+1) at IF (sc1):
// a single load is both sync-detect and data -> 1 IF RTT per hop (was 3:
// drain+publish, flag poll, data load). No flags, no h1 trace, no fences.
//  - rh1 ring [8][64][512]: L0 h output; consumed by L0 (self, t-1) and L1 (t).
//  - r2  ring [2][64][512]: L1 h self-recurrence; also L0's lag-throttle probe
//    (L0 overwrites rh1 slot t&7 only when a sibling L1 tag >= t-6).
// Each WG: 16 batch rows x 32 h-cols, 4 waves (wave = gate), W in 256 AGPRs.
// L0 pre-computes x(t+1)@Wx overlapped with the ring-poll for h(t) (MFMA
// hides the IF RTT); only K=512 (h-half) remains on the serial path.

typedef short short8 __attribute__((ext_vector_type(8)));
typedef float f32x4 __attribute__((ext_vector_type(4)));

#define NT 1024
#define NB 64
#define NH 512
// retry iter ~= one IF RTT (~0.5us) -> cap ~2ms/site; legit retries are <10.
#define SPIN_CAP 4000u

// Z_lds column swizzle: flips col bit4 keyed by row parity ^ row bit2.
#define ZSWZ(row, col) ((col) ^ ((((row) ^ ((row) >> 2)) & 1) << 4))

#define LD64(p) __hip_atomic_load((const unsigned long long*)(p), __ATOMIC_RELAXED, __HIP_MEMORY_SCOPE_AGENT)
#define LD32(p) __hip_atomic_load((const unsigned*)(p), __ATOMIC_RELAXED, __HIP_MEMORY_SCOPE_AGENT)
#define ST32(p, v) __hip_atomic_store((unsigned*)(p), (v), __ATOMIC_RELAXED, __HIP_MEMORY_SCOPE_AGENT)

// raw workgroup barrier: LDS-ordering only, does NOT drain vmcnt (in-flight
// ring/out stores keep flying). sched_barrier stops MFMA hoisting (rule #18).
#define RAW_BAR() do { \
    asm volatile("s_waitcnt lgkmcnt(0)" ::: "memory"); \
    __builtin_amdgcn_s_barrier(); \
    __builtin_amdgcn_sched_barrier(0); \
} while (0)

static __device__ __forceinline__ unsigned short f2bf(float f) {
    union { float f; unsigned u; } v; v.f = f;
    unsigned r = (v.u + 0x7fffu + ((v.u >> 16) & 1u)) >> 16;  // RNE
    return (unsigned short)r;
}
static __device__ __forceinline__ float sigf(float x) {
    return 1.0f / (1.0f + __expf(-x));
}
static __device__ __forceinline__ float tanh_fast(float x) {
    return 1.0f - 2.0f / (1.0f + __expf(2.0f * x));
}

// X [64][1024][512] f32 -> Xt [1024][64][512] bf16
__global__ void cvt_x_kernel(const float* __restrict__ X, unsigned short* __restrict__ Xt) {
    unsigned id = blockIdx.x * 256 + threadIdx.x;
    unsigned d8 = id & 63u;
    unsigned t  = (id >> 6) & 1023u;
    unsigned b  = id >> 16;
    const f32x4* src = (const f32x4*)(X + (((size_t)b * NT + t) * NH) + d8 * 8);
    f32x4 v0 = src[0], v1 = src[1];
    short8 o;
    #pragma unroll
    for (int j = 0; j < 4; ++j) o[j] = (short)f2bf(v0[j]);
    #pragma unroll
    for (int j = 0; j < 4; ++j) o[4 + j] = (short)f2bf(v1[j]);
    *(short8*)(Xt + (((size_t)t * NB + b) * NH) + d8 * 8) = o;
}

// W[l] [1024][2048] f32 -> Wp [l][wgi][g][h][c16][k1024] bf16 (B-fragment order)
__global__ void pack_w_kernel(const float* __restrict__ W1, const float* __restrict__ W2,
                              unsigned short* __restrict__ Wp) {
    unsigned id = blockIdx.x * 256 + threadIdx.x;
    unsigned k8  = id & 127u;
    unsigned c   = (id >> 7) & 15u;
    unsigned h   = (id >> 11) & 1u;
    unsigned g   = (id >> 12) & 3u;
    unsigned wgi = (id >> 14) & 15u;
    unsigned l   = id >> 18;
    const float* W = l ? W2 : W1;
    unsigned n = g * 512u + wgi * 32u + h * 16u + c;
    short8 o;
    #pragma unroll
    for (int j = 0; j < 8; ++j) o[j] = (short)f2bf(W[(size_t)(k8 * 8 + j) * 2048 + n]);
    *(short8*)(Wp + (size_t)id * 8) = o;
}

__global__ __launch_bounds__(256, 1)
void lstm_kernel(const unsigned short* __restrict__ Xt,   // [1024][64][512] bf16
                 unsigned* __restrict__ rh1,              // [8][64][512] tagged u32
                 unsigned* __restrict__ r2,               // [2][64][512] tagged u32
                 const unsigned short* __restrict__ Wp,   // packed weights bf16
                 const float* __restrict__ b1,
                 const float* __restrict__ b2,
                 float* __restrict__ out)                 // [64][1024][512] f32
{
    const int bi  = blockIdx.x;
    const int L   = (bi >> 2) & 1;    // bi&7 -> (L,isl): island per XCD heuristic
    const int isl = bi & 3;
    const int wgi = bi >> 3;          // 0..15
    const int tid = threadIdx.x;
    const int wv  = tid >> 6;         // wave index == gate index (i,j,f,o)
    const int ln  = tid & 63;

    __shared__ alignas(16) unsigned short A_lds[16 * 1024]; // [16 rows][1024 k], XOR-swizzled
    __shared__ float Z_lds[16 * 128];                       // [16 rows][4 gates * 32 hcols]

    const int lc = ln & 15;
    const int lk = ln >> 4;
    const char* ab = (const char*)A_lds + lc * 2048;
    const int sw = lc & 7;

    // ---- persistent weight fragments: wave wv, cols n = wv*512 + wgi*32 + {0..31}
    // wf[0..15] = K rows 0..511 (x-half), wf[16..31] = K rows 512..1023 (h-half)
    short8 wf0[32], wf1[32];
    {
        const unsigned short* wb = Wp + ((((size_t)L * 16 + wgi) * 4 + wv) * 2) * (16 * 1024);
        #pragma unroll
        for (int ks = 0; ks < 32; ++ks) {
            wf0[ks] = *(const short8*)(wb + (size_t)lc * 1024 + ks * 32 + lk * 8);
            wf1[ks] = *(const short8*)(wb + (size_t)(16 + lc) * 1024 + ks * 32 + lk * 8);
        }
    }

    float c0 = 0.0f, c1 = 0.0f;
    const int er = tid >> 4;          // row 0..15 (elementwise ownership)
    const int ej = tid & 15;
    const int brow_e = isl * 16 + er;

    const float* bias = L ? b2 : b1;
    const int jg0 = wgi * 32 + ej, jg1 = jg0 + 16;
    const float bi_i0 = bias[jg0],          bi_i1 = bias[jg1];
    const float bi_j0 = bias[512 + jg0],    bi_j1 = bias[512 + jg1];
    const float bi_f0 = bias[1024 + jg0] + 1.0f, bi_f1 = bias[1024 + jg1] + 1.0f;
    const float bi_o0 = bias[1536 + jg0],   bi_o1 = bias[1536 + jg1];

    // staging map: thread (wv,ln) owns rows {wv,wv+4,wv+8,wv+12}, cols ln*8..+8
    const int rb = isl * 16;
    // lag-throttle probe words (L0 only): own (row,col) in both r2 slots
    const unsigned* lag0p = r2 + (size_t)brow_e * 512 + jg0;
    const unsigned* lag1p = lag0p + 2 * 32768 / 2;   // + 64*512

    f32x4 a00 = {0,0,0,0}, a01 = {0,0,0,0}, a10 = {0,0,0,0}, a11 = {0,0,0,0};

    auto issue_ring = [&](const unsigned* slot, unsigned long long* rr) {
        #pragma unroll
        for (int p = 0; p < 4; ++p) {
            const unsigned* q = slot + ((size_t)(rb + wv + 4 * p)) * 512 + ln * 8;
            rr[4 * p + 0] = LD64(q + 0);
            rr[4 * p + 1] = LD64(q + 2);
            rr[4 * p + 2] = LD64(q + 4);
            rr[4 * p + 3] = LD64(q + 6);
        }
    };
    auto tags_ok = [&](const unsigned long long* rr, unsigned tagv) -> bool {
        bool ok = true;
        #pragma unroll
        for (int i = 0; i < 16; ++i)
            ok &= ((unsigned)(rr[i] & 0xffffu) == tagv) &
                  ((unsigned)((rr[i] >> 32) & 0xffffu) == tagv);
        return ok;
    };
    auto stage_ring = [&](const unsigned long long* rr, int half) {
        #pragma unroll
        for (int p = 0; p < 4; ++p) {
            short8 v;
            #pragma unroll
            for (int j = 0; j < 4; ++j) {
                unsigned long long q = rr[4 * p + j];
                v[2 * j]     = (short)(unsigned short)(q >> 16);
                v[2 * j + 1] = (short)(unsigned short)(q >> 48);
            }
            int r = wv + 4 * p;
            *(short8*)((char*)A_lds + r * 2048 + (((half * 64 + ln) ^ (r & 7)) << 4)) = v;
        }
    };
    auto load_x = [&](int t, short8* xr) {
        const unsigned short* xsrc = Xt + (size_t)t * (NB * NH);
        #pragma unroll
        for (int p = 0; p < 4; ++p)
            xr[p] = *(const short8*)(xsrc + (size_t)(rb + wv + 4 * p) * NH + ln * 8);
    };
    auto write_x = [&](const short8* xr) {
        #pragma unroll
        for (int p = 0; p < 4; ++p) {
            int r = wv + 4 * p;
            *(short8*)((char*)A_lds + r * 2048 + ((ln ^ (r & 7)) << 4)) = xr[p];
        }
    };
    auto gemm_half = [&](int base, const short8* w0, const short8* w1) {
        #pragma unroll
        for (int ks = 0; ks < 16; ++ks) {
            short8 a = *(const short8*)(ab + ((base + ((ks * 4 + lk) ^ sw)) << 4));
            if (ks & 1) {
                a01 = __builtin_amdgcn_mfma_f32_16x16x32_bf16(a, w0[ks], a01, 0, 0, 0);
                a11 = __builtin_amdgcn_mfma_f32_16x16x32_bf16(a, w1[ks], a11, 0, 0, 0);
            } else {
                a00 = __builtin_amdgcn_mfma_f32_16x16x32_bf16(a, w0[ks], a00, 0, 0, 0);
                a10 = __builtin_amdgcn_mfma_f32_16x16x32_bf16(a, w1[ks], a10, 0, 0, 0);
            }
        }
    };
    auto zero_acc = [&]() {
        a00 = {0,0,0,0}; a01 = {0,0,0,0}; a10 = {0,0,0,0}; a11 = {0,0,0,0};
    };
    // gates + state update + tagged h stores; Z-barrier inside.
    auto finish = [&](int t) {
        f32x4 z0 = a00 + a01, z1 = a10 + a11;
        #pragma unroll
        for (int q = 0; q < 4; ++q) {
            int row = lk * 4 + q;                 // C/D: row=(lane>>4)*4+reg, col=lane&15
            Z_lds[row * 128 + ZSWZ(row, wv * 32 + lc)]      = z0[q];
            Z_lds[row * 128 + ZSWZ(row, wv * 32 + 16 + lc)] = z1[q];
        }
        __syncthreads();
        const float* zr = Z_lds + er * 128;
        const unsigned tagv = (unsigned)(t + 1);
        unsigned* hdst = L ? (r2 + (size_t)(t & 1) * 32768) : (rh1 + (size_t)(t & 7) * 32768);
        {
            float iv = zr[ZSWZ(er, ej)]       + bi_i0;
            float gv = zr[ZSWZ(er, 32 + ej)]  + bi_j0;
            float fv = zr[ZSWZ(er, 64 + ej)]  + bi_f0;   // includes FORGET_BIAS
            float ov = zr[ZSWZ(er, 96 + ej)]  + bi_o0;
            c0 = c0 * sigf(fv) + sigf(iv) * tanh_fast(gv);
            float hv = tanh_fast(c0) * sigf(ov);
            ST32(hdst + (size_t)brow_e * 512 + jg0, ((unsigned)f2bf(hv) << 16) | tagv);
            if (L) out[((size_t)brow_e * NT + t) * NH + jg0] = hv;
        }
        {
            float iv = zr[ZSWZ(er, 16 + ej)]  + bi_i1;
            float gv = zr[ZSWZ(er, 48 + ej)]  + bi_j1;
            float fv = zr[ZSWZ(er, 80 + ej)]  + bi_f1;
            float ov = zr[ZSWZ(er, 112 + ej)] + bi_o1;
            c1 = c1 * sigf(fv) + sigf(iv) * tanh_fast(gv);
            float hv = tanh_fast(c1) * sigf(ov);
            ST32(hdst + (size_t)brow_e * 512 + jg1, ((unsigned)f2bf(hv) << 16) | tagv);
            if (L) out[((size_t)brow_e * NT + t) * NH + jg1] = hv;
        }
    };

    if (L == 0) {
        short8 xr[4];
        unsigned long long rr[16];
        unsigned la0 = 0, la1 = 0;

        load_x(0, xr);
        write_x(xr);
        __syncthreads();
        zero_acc();
        gemm_half(0, wf0, wf1);             // x(0)@Wx
        load_x(1, xr);                      // park x(1)

        for (int t = 0; t < NT; ++t) {
            if (t > 0) {
                // rr (h(t-1), tag t) issued at end of prev iter, overlapped w/ gemm_x
                const unsigned tagv = (unsigned)t;
                unsigned sp = 0;
                while (!tags_ok(rr, tagv) && ++sp < SPIN_CAP)
                    issue_ring(rh1 + (size_t)((t - 1) & 7) * 32768, rr);
                if (t >= 8) {   // lag-throttle: sibling L1 tag >= t-6 before slot reuse
                    unsigned lmin = (unsigned)(t - 6);
                    while (((la0 & 0xffffu) < lmin) && ((la1 & 0xffffu) < lmin)
                           && ++sp < SPIN_CAP) { la0 = LD32(lag0p); la1 = LD32(lag1p); }
                }
                stage_ring(rr, 1);
                __syncthreads();
                gemm_half(64, wf0 + 16, wf1 + 16);   // += h(t-1)@Wh
            }
            finish(t);
            if (t + 1 < NT) {
                write_x(xr);                // x(t+1) -> slots 0..63
                RAW_BAR();                  // LDS-order only; h stores keep flying
                zero_acc();
                issue_ring(rh1 + (size_t)(t & 7) * 32768, rr);   // h(t), tag t+1
                if (t + 1 >= 8) { la0 = LD32(lag0p); la1 = LD32(lag1p); }
                if (t + 2 < NT) load_x(t + 2, xr);
                __builtin_amdgcn_sched_barrier(0);
                gemm_half(0, wf0, wf1);     // x(t+1)@Wx overlaps the ring RTT
            }
        }
    } else {
        unsigned long long rrA[16];   // ring_h1 (x-half = h1[t])
        unsigned long long rrB[16];   // r2 (h-half = h2[t-1])

        zero_acc();
        issue_ring(rh1, rrA);         // h1[0], tag 1

        for (int t = 0; t < NT; ++t) {
            if (t > 0) {
                // rrB (h2(t-1), tag t) issued at end of prev iter
                const unsigned tagB = (unsigned)t;
                unsigned sp = 0;
                while (!tags_ok(rrB, tagB) && ++sp < SPIN_CAP)
                    issue_ring(r2 + (size_t)((t - 1) & 1) * 32768, rrB);
                stage_ring(rrB, 1);
                __syncthreads();
                issue_ring(rh1 + (size_t)(t & 7) * 32768, rrA);  // h1[t], tag t+1
                __builtin_amdgcn_sched_barrier(0);
                gemm_half(64, wf0 + 16, wf1 + 16);   // += h2(t-1)@Wh (hides rrA RTT)
            }
            {
                const unsigned tagA = (unsigned)(t + 1);
                unsigned sp = 0;
                while (!tags_ok(rrA, tagA) && ++sp < SPIN_CAP)
                    issue_ring(rh1 + (size_t)(t & 7) * 32768, rrA);
                stage_ring(rrA, 0);
                __syncthreads();
                gemm_half(0, wf0, wf1);              // += h1(t)@Wx2
            }
            finish(t);
            if (t + 1 < NT) {
                zero_acc();
                issue_ring(r2 + (size_t)(t & 1) * 32768, rrB);   // h2(t), tag t+1
            }
        }
    }
}

extern "C" void kernel_launch(void* const* d_in, const int* in_sizes, int n_in,
                              void* d_out, int out_size, void* d_ws, size_t ws_size,
                              hipStream_t stream) {
    (void)in_sizes; (void)n_in; (void)out_size;
    const float* X  = (const float*)d_in[0];
    const float* W1 = (const float*)d_in[1];
    const float* b1 = (const float*)d_in[2];
    const float* W2 = (const float*)d_in[3];
    const float* b2 = (const float*)d_in[4];
    float* out = (float*)d_out;

    char* ws = (char*)d_ws;
    const size_t sz_rh1 = (size_t)8 * 64 * 512 * 4;            // 1 MB tagged ring
    const size_t sz_r2  = (size_t)2 * 64 * 512 * 4;            // 256 KB tagged ring
    const size_t o_rh1 = 0;
    const size_t o_r2  = o_rh1 + sz_rh1;
    const size_t o_xt  = o_r2 + sz_r2;                         // Xt bf16: 64 MB
    const size_t o_wp  = o_xt + (size_t)NT * NB * NH * 2;      // packed W: 8 MB
    const size_t o_end = o_wp + (size_t)2 * 16 * 4 * 2 * 16 * 1024 * 2;
    if (ws_size < o_end) return;  // clean validation failure, not memory corruption

    unsigned* rh1 = (unsigned*)(ws + o_rh1);
    unsigned* r2  = (unsigned*)(ws + o_r2);
    unsigned short* Xt = (unsigned short*)(ws + o_xt);
    unsigned short* Wp = (unsigned short*)(ws + o_wp);

    hipMemsetAsync(ws + o_rh1, 0, sz_rh1 + sz_r2, stream);  // tag 0 = invalid
    cvt_x_kernel<<<16384, 256, 0, stream>>>(X, Xt);
    pack_w_kernel<<<2048, 256, 0, stream>>>(W1, W2, Wp);
    lstm_kernel<<<128, 256, 0, stream>>>(Xt, rh1, r2, Wp, b1, b2, out);
}